// Round 6
// baseline (187.852 us; speedup 1.0000x reference)
//
#include <hip/hip_runtime.h>

// SpatialCorrelationSampler via MFMA Gram-band:
//   out[b,(dy+4)*9+(dx+4),y,x] = sum_c f0[b,c,y,x]*f1[b,c,y+dy,x+dx]
// B=4 C=256 H=96 W=160, dy,dx in [-4,4], OOB=0. Out (4,81,96,160) fp32.
//
// R6 = R5 with compile fix only: __builtin_amdgcn_cvt_pkrtz returns
// __fp16-vec2, not _Float16-vec2 -> pack through __fp16-typed unions.
//
// Design (R5): per (y,dy), G = f0_row x f1_row^T over K=256 ch; out = 9-wide
// band. M-tile 16 f0 px, N-window 32 f1 px (2x mfma_f32_16x16x32_f16, fp16
// RTZ in, fp32 acc; 3.55x FLOP waste -> ~4.4us MFMA pipe). Block = 8 waves;
// wave w = row y0+w, all 9 dy (acc[9][2] f32x4 = 72 regs). K chunked x32;
// f1 chunk (16 rows x 32 px x 32 ch fp16) staged in LDS (px stride 20 dw:
// b128-aligned, balanced banks); f0 A-frags direct from global. Exactly-once
// coverage -> plain stores, no atomics. Frag pattern: px = lane&15,
// ch = quad*8+j (m97-verified).

using pkh2_t  = __attribute__((ext_vector_type(2))) __fp16;   // cvt_pkrtz result
using half8_t = __attribute__((ext_vector_type(8))) _Float16; // MFMA operand
using f32x4_t = __attribute__((ext_vector_type(4))) float;

#define Bn 4
#define Cn 256
#define Hn 96
#define Wn 160
#define HWn (Hn * Wn)
#define NP 81
#define YS 8              // output rows per block = 8 waves
#define MT 16             // output x per block (MFMA M)
#define KC 32             // channels per chunk (MFMA K)
#define NCHK (Cn / KC)    // 8
#define WR (YS + 8)       // 16 staged f1 rows
#define WP 32             // staged f1 window px (2 N-tiles, x0-8..x0+23)
#define PXD 20            // dwords per px: 16 data (32 fp16) + 4 pad
#define ROWD (WP * PXD)   // 640
#define BUFD (WR * ROWD)  // 10240 dwords = 40 KB
#define NT 512

__global__ __launch_bounds__(NT, 2) void corr_mfma(const float* __restrict__ f0,
                                                   const float* __restrict__ f1,
                                                   float* __restrict__ out) {
    __shared__ __align__(16) unsigned int lds[BUFD];

    const int tid  = threadIdx.x;
    const int w    = tid >> 6;        // wave 0..7 -> output row y0+w
    const int lane = tid & 63;
    const int q    = lane >> 4;       // quad: ch block q*8+j in frags
    const int n    = lane & 15;       // px: M-index for A, N-index for B/D

    // XCD-spatial swizzle (R4-proven): xcd gets (batch, y-half)
    const int blk = blockIdx.x;       // 0..479
    const int xcd = blk & 7;
    const int it  = blk >> 3;         // 0..59
    const int b   = xcd >> 1;
    const int ys  = (xcd & 1) * 6 + it / 10;   // 0..11
    const int xt  = it % 10;
    const int y0  = ys * YS;
    const int x0  = xt * MT;
    const int y   = y0 + w;

    // ---- f1 staging map: thread -> (row rr, px group pxg(4 px), ch slot cs(8 ch))
    const int rr  = tid >> 5;         // 0..15  -> f1 row y0-4+rr
    const int pxg = (tid >> 2) & 7;   // 0..7   -> window px 4*pxg..+3
    const int cs  = tid & 3;          // ch base cs*8 within chunk
    const int gy  = y0 - 4 + rr;
    const int gx  = x0 - 8 + pxg * 4;           // mult of 4: float4 all-in/out
    const bool sv = (gy >= 0) && (gy < Hn) && (gx >= 0) && (gx < Wn);
    const float4* __restrict__ f1v = (const float4*)f1;
    const int sg0 = sv ? ((((b * Cn) * Hn + gy) * Wn + gx) >> 2) : 0;  // + c*(HWn/4)
    const int ldw = rr * ROWD + (pxg * 4) * PXD + cs * 4;

    // A-frag loads: f0[(b*Cn+c)*HW + y*W + x0+n], c = chunk*KC + q*8 + j
    const float* __restrict__ f0p = f0 + (b * Cn) * HWn + y * Wn + x0 + n;

    f32x4_t acc[9][2];
#pragma unroll
    for (int d = 0; d < 9; ++d)
#pragma unroll
        for (int t = 0; t < 2; ++t) acc[d][t] = (f32x4_t){0.f, 0.f, 0.f, 0.f};

    // ---- prologue: prefetch chunk 0 (8 f1 float4 + 8 f0 scalars per thread)
    float4 F[8];
    float  A[8];
#pragma unroll
    for (int j = 0; j < 8; ++j) {
        const int c = cs * 8 + j;
        F[j] = sv ? f1v[sg0 + c * (HWn / 4)] : make_float4(0.f, 0.f, 0.f, 0.f);
        A[j] = f0p[(q * 8 + j) * HWn];
    }

    for (int ch = 0; ch < NCHK; ++ch) {
        __syncthreads();   // all waves done reading lds from previous chunk
        // pack fp32->fp16 (RTZ) and write f1 chunk: 4 px, one b128 each
#pragma unroll
        for (int i = 0; i < 4; ++i) {
            union { pkh2_t h2[4]; uint4 u4; } u;
#pragma unroll
            for (int k = 0; k < 4; ++k) {
                const float lo = ((const float*)&F[2 * k])[i];
                const float hi = ((const float*)&F[2 * k + 1])[i];
                u.h2[k] = __builtin_amdgcn_cvt_pkrtz(lo, hi);
            }
            *(uint4*)&lds[ldw + i * PXD] = u.u4;
        }
        // build A-frag for this chunk (before A[] is overwritten)
        union { pkh2_t h2[4]; half8_t h8; } ua;
#pragma unroll
        for (int k = 0; k < 4; ++k)
            ua.h2[k] = __builtin_amdgcn_cvt_pkrtz(A[2 * k], A[2 * k + 1]);
        const half8_t afrag = ua.h8;
        __syncthreads();

        // prefetch next chunk; in flight across the 18 MFMAs
        if (ch + 1 < NCHK) {
            const int cb = (ch + 1) * KC;
#pragma unroll
            for (int j = 0; j < 8; ++j) {
                const int c = cb + cs * 8 + j;
                F[j] = sv ? f1v[sg0 + c * (HWn / 4)] : make_float4(0.f, 0.f, 0.f, 0.f);
                A[j] = f0p[(cb + q * 8 + j) * HWn];
            }
        }

        // 9 dy x 2 N-tiles MFMAs; B-frag: px = Nt*16+n of row w+d, ch q*8..+7
#pragma unroll
        for (int d = 0; d < 9; ++d) {
            const unsigned int* rp = &lds[(w + d) * ROWD + n * PXD + q * 4];
#pragma unroll
            for (int t = 0; t < 2; ++t) {
                const half8_t bfrag = *(const half8_t*)(rp + t * 16 * PXD);
                acc[d][t] = __builtin_amdgcn_mfma_f32_16x16x32_f16(afrag, bfrag,
                                                                   acc[d][t], 0, 0, 0);
            }
        }
    }

    // ---- epilogue: D[m = q*4+r][n]; dx = (Nt*16+n) - 8 - m; keep |dx|<=4.
    // Each (m,dx) covered exactly once across the two N-tiles -> plain stores.
#pragma unroll
    for (int d = 0; d < 9; ++d)
#pragma unroll
        for (int t = 0; t < 2; ++t)
#pragma unroll
            for (int r = 0; r < 4; ++r) {
                const int m  = q * 4 + r;
                const int dx = t * 16 + n - 8 - m;
                if (dx >= -4 && dx <= 4) {
                    const int p = d * 9 + dx + 4;
                    out[((b * NP + p) * Hn + y) * Wn + x0 + m] = acc[d][t][r];
                }
            }
}

extern "C" void kernel_launch(void* const* d_in, const int* in_sizes, int n_in,
                              void* d_out, int out_size, void* d_ws, size_t ws_size,
                              hipStream_t stream) {
    const float* f0 = (const float*)d_in[0];
    const float* f1 = (const float*)d_in[1];
    float* out = (float*)d_out;
    corr_mfma<<<dim3(480), NT, 0, stream>>>(f0, f1, out);
}